// Round 4
// baseline (205.267 us; speedup 1.0000x reference)
//
#include <hip/hip_runtime.h>
#include <hip/hip_bf16.h>
#include <math.h>

#define BB 4
#define NN 4096
#define CCH 256
#define HEADS 8
#define HD 32
#define NKV 1024
#define EPS_LN 1e-5f
#define GRIDN 256

typedef short short8 __attribute__((ext_vector_type(8)));
typedef float floatx4 __attribute__((ext_vector_type(4)));

// scale = HD^-0.5 folded with log2(e): softmax runs in exp2 domain
#define QSCALE (0.17677669529663687f * 1.4426950408889634f)

__device__ __forceinline__ unsigned pk_bf16(float a, float b) {
  __hip_bfloat162 h = __float22bfloat162_rn(make_float2(a, b));
  unsigned u; __builtin_memcpy(&u, &h, 4); return u;
}

__device__ __forceinline__ short8 cvt8(float4 a, float4 b) {
  union { short8 s; unsigned u[4]; } r;
  r.u[0] = pk_bf16(a.x, a.y); r.u[1] = pk_bf16(a.z, a.w);
  r.u[2] = pk_bf16(b.x, b.y); r.u[3] = pk_bf16(b.z, b.w);
  return r.s;
}

// X-tile LDS layout (tokens x 32 16B-units, 33-unit skew)
#define XU16(t, u) (((t) * 33 + (u)) * 8)

// Grid-wide barrier: safe because all 256 blocks are co-resident
// (grid == 256 CUs, 8 waves/block = 2 waves/SIMD @ <=256 VGPR, 68KB LDS).
// Writers did their stores before this; fence + device-scope atomic +
// acquire spin on one lane per block.
__device__ __forceinline__ void grid_barrier(unsigned* ctr) {
  __syncthreads();
  if (threadIdx.x == 0) {
    __threadfence();
    atomicAdd(ctr, 1u);
    while (__hip_atomic_load(ctr, __ATOMIC_ACQUIRE, __HIP_MEMORY_SCOPE_AGENT) < GRIDN) {
      __builtin_amdgcn_s_sleep(1);
    }
  }
  __syncthreads();
}

// ---------------------------------------------------------------------------
// ONE persistent kernel, 256 blocks x 512 thr, 3 phases + 2 grid barriers:
//  P0: cast weights fp32->bf16 (fragment-major swizzle; QSCALE folded in q_w;
//      sr_w K permuted quadrant-major).
//  P1: per block: conv+LN+KV tile bx (8-wave split) then 2 Q-proj tiles.
//  P2: fused flash-attention + output projection (wave = head, 64 tok/block).
// Removes 2 kernel boundaries vs the 3-kernel pipeline.
// ---------------------------------------------------------------------------
__global__ __launch_bounds__(512) void sra_fused(
    const float* __restrict__ x,
    const float* __restrict__ q_w, const float* __restrict__ q_b,
    const float* __restrict__ kv_w, const float* __restrict__ kv_b,
    const float* __restrict__ sr_w, const float* __restrict__ sr_b,
    const float* __restrict__ ln_g, const float* __restrict__ ln_b,
    const float* __restrict__ proj_w, const float* __restrict__ proj_b,
    unsigned short* __restrict__ q_wbf, unsigned short* __restrict__ kv_wbf,
    unsigned short* __restrict__ sr_wbf, unsigned short* __restrict__ proj_wbf,
    unsigned short* __restrict__ qbf, unsigned short* __restrict__ kbf,
    unsigned short* __restrict__ vtbf,
    unsigned* __restrict__ bar, float* __restrict__ out) {
  __shared__ unsigned short sm[34816];   // 68 KB, reused across phases
  const int tid = threadIdx.x, bx = blockIdx.x;
  const int w = tid >> 6, ln = tid & 63;
  const int l15 = ln & 15, qd = ln >> 4;

  // ================= P0: weight cast =================
  {
    const int idx = bx * 512 + tid;       // 131072 threads, 65536 units
    if (idx < 65536) {
      const int e = idx * 8;
      if (e >= 196608 && e < 458752) {
        // sr_w: 8 consecutive src elems = (row, c0..c0+1, q0..3), c0 even
        const int off = e - 196608;
        const int row = off >> 10;
        const int wr = off & 1023;
        const int c0 = (wr >> 3) * 2;
        float4 a = *(const float4*)&sr_w[off];
        float4 b = *(const float4*)&sr_w[off + 4];
        const float v[8] = {a.x, a.y, a.z, a.w, b.x, b.y, b.z, b.w};
        const int base = (row >> 4) * 32;   // Kd/32 = 32
#pragma unroll
        for (int q = 0; q < 4; ++q) {
          const int unit = (base + q * 8 + (c0 >> 5)) * 64 + ((c0 >> 3) & 3) * 16 + (row & 15);
          *(unsigned*)&sr_wbf[unit * 8 + (c0 & 7)] = pk_bf16(v[q], v[4 + q]);
        }
      } else {
        const float* src; unsigned short* dst; int off; float sc = 1.f;
        if (e < 65536)       { src = q_w;    dst = q_wbf;    off = e;          sc = QSCALE; }
        else if (e < 196608) { src = kv_w;   dst = kv_wbf;   off = e - 65536; }
        else                 { src = proj_w; dst = proj_wbf; off = e - 458752; }
        const int row = off >> 8;
        const int col = off & 255;
        const int unit = ((row >> 4) * 8 + (col >> 5)) * 64 + ((col >> 3) & 3) * 16 + (row & 15);
        float4 a = *(const float4*)&src[off];
        float4 b = *(const float4*)&src[off + 4];
        a.x *= sc; a.y *= sc; a.z *= sc; a.w *= sc;
        b.x *= sc; b.y *= sc; b.z *= sc; b.w *= sc;
        *(short8*)&dst[unit * 8] = cvt8(a, b);
      }
    }
  }
  grid_barrier(bar + 0);

  // ================= P1a: conv + LN + KV tile bx (8 waves) =================
  {
    unsigned short* xs = sm + 16512;
    const int gt0 = bx * 16;
    const int b = gt0 >> 10, tl = gt0 & 1023;
    const int ti = (tl & 1023) >> 5;
    const int cbase = 2 * (tl & 31);
    // coalesced patch staging: 64 x-tokens x 256 ch fp32, quadrant-major dst.
#pragma unroll
    for (int it = 0; it < 4; ++it) {
      const int g = it * 512 + tid;     // 0..2047 16B-units
      const int xt = g >> 5, u = g & 31;
      const int di = xt >> 5, cj = xt & 31;
      const int row = (2 * ti + di) * 64 + cbase + cj;
      const float* s = &x[((size_t)b * NN + row) * CCH + u * 8];
      float4 a = *(const float4*)s;
      float4 b2 = *(const float4*)(s + 4);
      const int tk = cj >> 1, q = di * 2 + (cj & 1);
      *(short8*)(sm + (tk * 129 + q * 32 + u) * 8) = cvt8(a, b2);
    }
    __syncthreads();
    floatx4 cacc[2];
#pragma unroll
    for (int ct = 0; ct < 2; ++ct) for (int r = 0; r < 4; ++r) cacc[ct][r] = 0.f;
    const unsigned short* wbc = sr_wbf + ln * 8;
#pragma unroll
    for (int kc = 0; kc < 32; ++kc) {
      short8 xf = *(const short8*)(sm + (l15 * 129 + kc * 4 + qd) * 8);
#pragma unroll
      for (int ct = 0; ct < 2; ++ct) {
        short8 wf = *(const short8*)(wbc + ((size_t)((w * 2 + ct) * 32 + kc)) * 512);
        cacc[ct] = __builtin_amdgcn_mfma_f32_16x16x32_bf16(wf, xf, cacc[ct], 0, 0, 0);
      }
    }
    __syncthreads();
    float* ft = (float*)sm;
#pragma unroll
    for (int ct = 0; ct < 2; ++ct) {
      float4 o;
      o.x = cacc[ct][0]; o.y = cacc[ct][1]; o.z = cacc[ct][2]; o.w = cacc[ct][3];
      *(float4*)&ft[l15 * 260 + (w * 2 + ct) * 16 + qd * 4] = o;
    }
    __syncthreads();
    if (tid < 256) {
      const int tk = tid >> 4, l16 = tid & 15;
      float v[16];
      float4* vv = (float4*)v;
#pragma unroll
      for (int m = 0; m < 4; ++m) {
        float4 t = *(float4*)&ft[tk * 260 + l16 * 16 + m * 4];
        float4 sb = *(const float4*)&sr_b[l16 * 16 + m * 4];
        t.x += sb.x; t.y += sb.y; t.z += sb.z; t.w += sb.w;
        vv[m] = t;
      }
      float s1 = 0.f, s2 = 0.f;
#pragma unroll
      for (int i = 0; i < 16; ++i) { s1 += v[i]; s2 += v[i] * v[i]; }
#pragma unroll
      for (int off = 1; off < 16; off <<= 1) {
        s1 += __shfl_xor(s1, off);
        s2 += __shfl_xor(s2, off);
      }
      const float mu = s1 * (1.f / 256.f);
      const float rstd = rsqrtf(s2 * (1.f / 256.f) - mu * mu + EPS_LN);
#pragma unroll
      for (int m = 0; m < 2; ++m) {
        float4 ga = *(const float4*)&ln_g[l16 * 16 + m * 8];
        float4 gb = *(const float4*)&ln_g[l16 * 16 + m * 8 + 4];
        float4 ba = *(const float4*)&ln_b[l16 * 16 + m * 8];
        float4 bb = *(const float4*)&ln_b[l16 * 16 + m * 8 + 4];
        float4 oa, ob;
        oa.x = (vv[m * 2].x - mu) * rstd * ga.x + ba.x;
        oa.y = (vv[m * 2].y - mu) * rstd * ga.y + ba.y;
        oa.z = (vv[m * 2].z - mu) * rstd * ga.z + ba.z;
        oa.w = (vv[m * 2].w - mu) * rstd * ga.w + ba.w;
        ob.x = (vv[m * 2 + 1].x - mu) * rstd * gb.x + bb.x;
        ob.y = (vv[m * 2 + 1].y - mu) * rstd * gb.y + bb.y;
        ob.z = (vv[m * 2 + 1].z - mu) * rstd * gb.z + bb.z;
        ob.w = (vv[m * 2 + 1].w - mu) * rstd * gb.w + bb.w;
        *(short8*)(xs + XU16(tk, l16 * 2 + m)) = cvt8(oa, ob);
      }
    }
    __syncthreads();
    // KV GEMM: waves 0-3 -> K, waves 4-7 -> V, 4 ct (64 ch) each
    const bool isV = (w >= 4);
    const int c16b = (w & 3) * 4;             // 16-ch granule base within K or V
    floatx4 kacc[4];
#pragma unroll
    for (int ct = 0; ct < 4; ++ct) for (int r = 0; r < 4; ++r) kacc[ct][r] = 0.f;
    const unsigned short* wb = kv_wbf + (size_t)(isV ? 16 + c16b : c16b) * 4096 + ln * 8;
    if (!isV) {
#pragma unroll
      for (int kc = 0; kc < 8; ++kc) {
        short8 xf = *(const short8*)(xs + XU16(l15, kc * 4 + qd));
#pragma unroll
        for (int ct = 0; ct < 4; ++ct) {
          short8 wf = *(const short8*)(wb + ((size_t)ct * 4096 + kc * 512));
          kacc[ct] = __builtin_amdgcn_mfma_f32_16x16x32_bf16(wf, xf, kacc[ct], 0, 0, 0);
        }
      }
      const int tok = tl + l15;
#pragma unroll
      for (int ct = 0; ct < 4; ++ct) {
        const int ch = (c16b + ct) * 16 + qd * 4;
        float4 bb = *(const float4*)&kv_b[ch];
        uint2 u;
        u.x = pk_bf16(kacc[ct][0] + bb.x, kacc[ct][1] + bb.y);
        u.y = pk_bf16(kacc[ct][2] + bb.z, kacc[ct][3] + bb.w);
        const int h = ch >> 5, d0 = ch & 31;
        *(uint2*)&kbf[((size_t)(b * HEADS + h) * NKV + tok) * HD + d0] = u;
      }
    } else {
#pragma unroll
      for (int kc = 0; kc < 8; ++kc) {
        short8 xf = *(const short8*)(xs + XU16(l15, kc * 4 + qd));
#pragma unroll
        for (int ct = 0; ct < 4; ++ct) {
          short8 wf = *(const short8*)(wb + ((size_t)ct * 4096 + kc * 512));
          kacc[ct] = __builtin_amdgcn_mfma_f32_16x16x32_bf16(xf, wf, kacc[ct], 0, 0, 0);
        }
      }
      // frag-major V store
      const int ccv = tl >> 6;
      const int base6 = (tl & 63) + qd * 4;
      const int kg = (base6 >> 5) & 1, kq = (base6 >> 3) & 3, j0 = base6 & 7;
#pragma unroll
      for (int ct = 0; ct < 4; ++ct) {
        const int vc = (w - 4) * 64 + ct * 16 + l15;
        const float bb = kv_b[vc + 256];
        uint2 u;
        u.x = pk_bf16(kacc[ct][0] + bb, kacc[ct][1] + bb);
        u.y = pk_bf16(kacc[ct][2] + bb, kacc[ct][3] + bb);
        const int hh = vc >> 5, d = vc & 31;
        const int half = d >> 4, dl = d & 15;
        const int unit = ((ccv * 2 + kg) * 2 + half) * 64 + kq * 16 + dl;
        *(uint2*)&vtbf[(size_t)(b * HEADS + hh) * 32768 + unit * 8 + j0] = u;
      }
    }
  }

  // ================= P1b: two Q-projection tiles (32 tok each, 8 waves) =====
#pragma unroll 1
  for (int qi = 0; qi < 2; ++qi) {
    const long tok0 = (long)(bx * 2 + qi) * 32;
    __syncthreads();           // sm reuse fence
    const float* Xg = x + tok0 * 256;
#pragma unroll
    for (int j = 0; j < 2; ++j) {
      const int idx = j * 512 + tid;
      const int tok = idx >> 5, u = idx & 31;
      float4 a = *(const float4*)(Xg + (size_t)tok * 256 + u * 8);
      float4 b = *(const float4*)(Xg + (size_t)tok * 256 + u * 8 + 4);
      *(short8*)(sm + XU16(tok, u)) = cvt8(a, b);
    }
    __syncthreads();
    const int cb = w & 3, th = w >> 2;
    floatx4 qacc[4];
#pragma unroll
    for (int ct = 0; ct < 4; ++ct) for (int r = 0; r < 4; ++r) qacc[ct][r] = 0.f;
    const unsigned short* wb = q_wbf + (size_t)(cb * 4) * 4096 + ln * 8;
#pragma unroll
    for (int kc = 0; kc < 8; ++kc) {
      short8 xf = *(const short8*)(sm + XU16(th * 16 + l15, kc * 4 + qd));
#pragma unroll
      for (int ct = 0; ct < 4; ++ct) {
        short8 wf = *(const short8*)(wb + ((size_t)ct * 4096 + kc * 512));
        qacc[ct] = __builtin_amdgcn_mfma_f32_16x16x32_bf16(wf, xf, qacc[ct], 0, 0, 0);
      }
    }
    const int tok = (int)tok0 + th * 16 + l15;
    const int b = tok >> 12, trow = tok & 4095;
#pragma unroll
    for (int ct = 0; ct < 4; ++ct) {
      const int ch = cb * 64 + ct * 16 + qd * 4;
      float4 bb = *(const float4*)&q_b[ch];
      uint2 u;
      u.x = pk_bf16(qacc[ct][0] + bb.x * QSCALE, qacc[ct][1] + bb.y * QSCALE);
      u.y = pk_bf16(qacc[ct][2] + bb.z * QSCALE, qacc[ct][3] + bb.w * QSCALE);
      const int h = ch >> 5, d0 = ch & 31;
      *(uint2*)&qbf[((size_t)(b * HEADS + h) * NN + trow) * HD + d0] = u;
    }
  }
  grid_barrier(bar + 1);

  // ================= P2: flash attention + output projection ================
  {
    const int g0 = bx * 64;
    const int b = g0 >> 12, trow0 = g0 & 4095;
    const int bh = b * HEADS + w;            // wave = head
    const unsigned short* kbase = kbf + (size_t)bh * NKV * HD;
    const unsigned short* vfb = vtbf + (size_t)bh * 32768;
    const int q0 = trow0 + l15;              // + qt*16
    short8 qf[4];
#pragma unroll
    for (int qt = 0; qt < 4; ++qt)
      qf[qt] = *(const short8*)(qbf + ((size_t)bh * NN + q0 + qt * 16) * HD + qd * 8);
    const short8 ones = {16256, 16256, 16256, 16256, 16256, 16256, 16256, 16256};
    floatx4 a0[4], a1[4], al[4];
#pragma unroll
    for (int qt = 0; qt < 4; ++qt)
#pragma unroll
      for (int r = 0; r < 4; ++r) { a0[qt][r] = 0.f; a1[qt][r] = 0.f; al[qt][r] = 0.f; }
    const int pu = w * 544;   // wave-private P base (16B units)

    short8 kfA[4], vA[4], kfB[4], vB[4];
#define LOADKV(KF, VV, CC) do {                                               \
    const unsigned short* kp = kbase + ((size_t)(CC) * 64 + l15) * HD + qd * 8; \
    _Pragma("unroll")                                                          \
    for (int t = 0; t < 4; ++t) (KF)[t] = *(const short8*)(kp + t * 16 * HD);  \
    const unsigned short* vp = vfb + ((size_t)(CC) * 256 + ln) * 8;            \
    _Pragma("unroll")                                                          \
    for (int u = 0; u < 4; ++u) (VV)[u] = *(const short8*)(vp + u * 512);      \
  } while (0)

#define CHUNK(KF, VV) do {                                                     \
    _Pragma("unroll")                                                          \
    for (int qt = 0; qt < 4; ++qt) {                                           \
      const int pq = pu + qt * 136;                                            \
      floatx4 s[4];                                                            \
      _Pragma("unroll")                                                        \
      for (int t = 0; t < 4; ++t) {                                            \
        floatx4 z; for (int r = 0; r < 4; ++r) z[r] = 0.f;                     \
        s[t] = __builtin_amdgcn_mfma_f32_16x16x32_bf16((KF)[t], qf[qt], z, 0, 0, 0); \
      }                                                                        \
      _Pragma("unroll")                                                        \
      for (int t = 0; t < 4; ++t) {                                            \
        uint2 pk;                                                              \
        pk.x = pk_bf16(__builtin_amdgcn_exp2f(s[t][0]), __builtin_amdgcn_exp2f(s[t][1])); \
        pk.y = pk_bf16(__builtin_amdgcn_exp2f(s[t][2]), __builtin_amdgcn_exp2f(s[t][3])); \
        const int unit = pq + (t >> 1) * 68 + ((t & 1) * 2 + (qd >> 1)) * 16 + l15; \
        *(uint2*)(sm + unit * 8 + (qd & 1) * 4) = pk;                          \
      }                                                                        \
      _Pragma("unroll")                                                        \
      for (int kg = 0; kg < 2; ++kg) {                                         \
        short8 pf = *(const short8*)(sm + (pq + kg * 68 + ln) * 8);            \
        a0[qt] = __builtin_amdgcn_mfma_f32_16x16x32_bf16((VV)[kg * 2], pf, a0[qt], 0, 0, 0);     \
        a1[qt] = __builtin_amdgcn_mfma_f32_16x16x32_bf16((VV)[kg * 2 + 1], pf, a1[qt], 0, 0, 0); \
        al[qt] = __builtin_amdgcn_mfma_f32_16x16x32_bf16(ones, pf, al[qt], 0, 0, 0);             \
      }                                                                        \
    }                                                                          \
  } while (0)

    LOADKV(kfA, vA, 0);
    for (int cc = 0; cc < 16; cc += 2) {
      LOADKV(kfB, vB, cc + 1);
      CHUNK(kfA, vA);
      if (cc + 2 < 16) LOADKV(kfA, vA, cc + 2);
      CHUNK(kfB, vB);
    }
#undef LOADKV
#undef CHUNK

    // ---- all waves done with P -> alias LDS with proj staging ----
    __syncthreads();
#pragma unroll
    for (int qt = 0; qt < 4; ++qt) {
      const float inv = 1.f / al[qt][0];
      const int t = qt * 16 + l15;                 // local token
      const int u0 = w * 4 + (qd >> 1);            // 16B-unit within row
      uint2 v0, v1;
      v0.x = pk_bf16(a0[qt][0] * inv, a0[qt][1] * inv);
      v0.y = pk_bf16(a0[qt][2] * inv, a0[qt][3] * inv);
      v1.x = pk_bf16(a1[qt][0] * inv, a1[qt][1] * inv);
      v1.y = pk_bf16(a1[qt][2] * inv, a1[qt][3] * inv);
      *(uint2*)(sm + XU16(t, u0) + (qd & 1) * 4) = v0;
      *(uint2*)(sm + XU16(t, u0 + 2) + (qd & 1) * 4) = v1;
    }
    __syncthreads();

    // ---- output projection in-block ----
    const int cb = w & 3, th = w >> 2;
    floatx4 pacc[2][4];
#pragma unroll
    for (int tt = 0; tt < 2; ++tt)
#pragma unroll
      for (int ct = 0; ct < 4; ++ct) for (int r = 0; r < 4; ++r) pacc[tt][ct][r] = 0.f;
    const unsigned short* wb = proj_wbf + (size_t)(cb * 4) * 4096 + ln * 8;
#pragma unroll
    for (int kc = 0; kc < 8; ++kc) {
      short8 wf[4];
#pragma unroll
      for (int ct = 0; ct < 4; ++ct) wf[ct] = *(const short8*)(wb + (ct * 8 + kc) * 512);
#pragma unroll
      for (int tt = 0; tt < 2; ++tt) {
        short8 xf = *(const short8*)(sm + XU16(th * 32 + tt * 16 + l15, kc * 4 + qd));
#pragma unroll
        for (int ct = 0; ct < 4; ++ct)
          pacc[tt][ct] = __builtin_amdgcn_mfma_f32_16x16x32_bf16(wf[ct], xf, pacc[tt][ct], 0, 0, 0);
      }
    }
    const int chb = cb * 64;
#pragma unroll
    for (int tt = 0; tt < 2; ++tt) {
      const long tok = (long)g0 + th * 32 + tt * 16 + l15;
#pragma unroll
      for (int ct = 0; ct < 4; ++ct) {
        const int ch = chb + ct * 16 + qd * 4;
        float4 bb = *(const float4*)&proj_b[ch];
        float4 o;
        o.x = pacc[tt][ct][0] + bb.x; o.y = pacc[tt][ct][1] + bb.y;
        o.z = pacc[tt][ct][2] + bb.z; o.w = pacc[tt][ct][3] + bb.w;
        *(float4*)&out[(size_t)tok * 256 + ch] = o;
      }
    }
  }
}

// ---------------------------------------------------------------------------
extern "C" void kernel_launch(void* const* d_in, const int* in_sizes, int n_in,
                              void* d_out, int out_size, void* d_ws, size_t ws_size,
                              hipStream_t stream) {
  const float* x      = (const float*)d_in[0];
  const float* q_w    = (const float*)d_in[1];
  const float* q_b    = (const float*)d_in[2];
  const float* kv_w   = (const float*)d_in[3];
  const float* kv_b   = (const float*)d_in[4];
  const float* sr_w   = (const float*)d_in[5];
  const float* sr_b   = (const float*)d_in[6];
  const float* ln_g   = (const float*)d_in[7];
  const float* ln_b   = (const float*)d_in[8];
  const float* proj_w = (const float*)d_in[9];
  const float* proj_b = (const float*)d_in[10];
  float* out = (float*)d_out;

  char* base = (char*)d_ws;
  const size_t MB = 1048576;
  unsigned short* q_wbf    = (unsigned short*)(base);                 // 128 KB
  unsigned short* kv_wbf   = (unsigned short*)(base + 131072);        // 256 KB
  unsigned short* sr_wbf   = (unsigned short*)(base + 393216);        // 512 KB
  unsigned short* proj_wbf = (unsigned short*)(base + 917504);        // 128 KB
  unsigned short* q_bf     = (unsigned short*)(base + 1 * MB);        // 8 MB
  unsigned short* k_bf     = (unsigned short*)(base + 9 * MB);        // 2 MB
  unsigned short* vt_bf    = (unsigned short*)(base + 11 * MB);       // 2 MB
  unsigned* bar            = (unsigned*)(base + 13 * MB);             // 16 B

  hipMemsetAsync(bar, 0, 16, stream);
  sra_fused<<<GRIDN, 512, 0, stream>>>(x, q_w, q_b, kv_w, kv_b, sr_w, sr_b,
                                       ln_g, ln_b, proj_w, proj_b,
                                       q_wbf, kv_wbf, sr_wbf, proj_wbf,
                                       q_bf, k_bf, vt_bf, bar, out);
}

// Round 5
// 163.435 us; speedup vs baseline: 1.2560x; 1.2560x over previous
//
#include <hip/hip_runtime.h>
#include <hip/hip_bf16.h>
#include <math.h>

#define BB 4
#define NN 4096
#define CCH 256
#define HEADS 8
#define HD 32
#define NKV 1024
#define EPS_LN 1e-5f

typedef short short8 __attribute__((ext_vector_type(8)));
typedef float floatx4 __attribute__((ext_vector_type(4)));

// scale = HD^-0.5 folded with log2(e): softmax runs in exp2 domain
#define QSCALE (0.17677669529663687f * 1.4426950408889634f)

__device__ __forceinline__ unsigned pk_bf16(float a, float b) {
  __hip_bfloat162 h = __float22bfloat162_rn(make_float2(a, b));
  unsigned u; __builtin_memcpy(&u, &h, 4); return u;
}

__device__ __forceinline__ short8 cvt8(float4 a, float4 b) {
  union { short8 s; unsigned u[4]; } r;
  r.u[0] = pk_bf16(a.x, a.y); r.u[1] = pk_bf16(a.z, a.w);
  r.u[2] = pk_bf16(b.x, b.y); r.u[3] = pk_bf16(b.z, b.w);
  return r.s;
}

// ---------------------------------------------------------------------------
// Cast weights fp32 -> bf16, FRAGMENT-MAJOR swizzle:
// unit(row,col) = ((row>>4)*(Kd/32) + (col>>5))*64 + ((col>>3)&3)*16 + (row&15)
// -> a wave's wf load is one contiguous 1KB segment. QSCALE folded into q_w.
// sr_w additionally gets K permuted to QUADRANT-MAJOR: col' = q*256 + c.
// ---------------------------------------------------------------------------
__global__ __launch_bounds__(256) void cast_weights(
    const float* __restrict__ q_w, const float* __restrict__ kv_w,
    const float* __restrict__ sr_w, const float* __restrict__ proj_w,
    unsigned short* __restrict__ q_wbf, unsigned short* __restrict__ kv_wbf,
    unsigned short* __restrict__ sr_wbf, unsigned short* __restrict__ proj_wbf) {
  const int e = (blockIdx.x * 256 + threadIdx.x) * 8;
  if (e >= 196608 && e < 458752) {
    // sr_w: 8 consecutive src elems = (row, c0..c0+1, q0..3), c0 even
    const int off = e - 196608;
    const int row = off >> 10;
    const int wr = off & 1023;
    const int c0 = (wr >> 3) * 2;
    float4 a = *(const float4*)&sr_w[off];
    float4 b = *(const float4*)&sr_w[off + 4];
    const float v[8] = {a.x, a.y, a.z, a.w, b.x, b.y, b.z, b.w};
    const int base = (row >> 4) * 32;   // Kd/32 = 32
#pragma unroll
    for (int q = 0; q < 4; ++q) {
      const int unit = (base + q * 8 + (c0 >> 5)) * 64 + ((c0 >> 3) & 3) * 16 + (row & 15);
      *(unsigned*)&sr_wbf[unit * 8 + (c0 & 7)] = pk_bf16(v[q], v[4 + q]);
    }
    return;
  }
  const float* src; unsigned short* dst; int off; float sc = 1.f;
  if (e < 65536)       { src = q_w;    dst = q_wbf;    off = e;          sc = QSCALE; }
  else if (e < 196608) { src = kv_w;   dst = kv_wbf;   off = e - 65536; }
  else                 { src = proj_w; dst = proj_wbf; off = e - 458752; }
  const int row = off >> 8;
  const int col = off & 255;
  const int unit = ((row >> 4) * 8 + (col >> 5)) * 64 + ((col >> 3) & 3) * 16 + (row & 15);
  float4 a = *(const float4*)&src[off];
  float4 b = *(const float4*)&src[off + 4];
  a.x *= sc; a.y *= sc; a.z *= sc; a.w *= sc;
  b.x *= sc; b.y *= sc; b.z *= sc; b.w *= sc;
  *(short8*)&dst[unit * 8] = cvt8(a, b);
}

// X-tile LDS layout (tokens x 32 16B-units, 33-unit skew)
#define XU16(t, u) (((t) * 33 + (u)) * 8)

// ---------------------------------------------------------------------------
// Fused (SR-conv + LN + KV-projection) + Q-projection, WEIGHT-AMORTIZED.
// Grid 384 x 256 thr: bx < 128 -> conv tile (32 kv tok = one full kv row;
// 512 KB sr_wbf stream amortized over 2x tokens); bx >= 128 -> Q tile
// (64 tok; q_wbf stream amortized 2x vs R3's 32-tok tiles).
// ---------------------------------------------------------------------------
__global__ __launch_bounds__(256) void qconv_gemm(const float* __restrict__ x,
    const unsigned short* __restrict__ q_wbf, const float* __restrict__ q_b,
    const unsigned short* __restrict__ sr_wbf, const float* __restrict__ sr_b,
    const float* __restrict__ ln_g, const float* __restrict__ ln_b,
    const unsigned short* __restrict__ kv_wbf, const float* __restrict__ kv_b,
    unsigned short* __restrict__ qbf,
    unsigned short* __restrict__ kbf, unsigned short* __restrict__ vtbf) {
  __shared__ unsigned short sm[41472];   // 82944 B: patch 33024 | xs 8448; ft aliases base
  const int tid = threadIdx.x, w = tid >> 6, lnn = tid & 63;
  const int l15 = lnn & 15, qd = lnn >> 4;

  if (blockIdx.x >= 128) {
    // ---------------- Q projection tile: 64 tokens ----------------
    const long tok0 = (long)(blockIdx.x - 128) * 64;
    const float* Xg = x + tok0 * 256;
#pragma unroll
    for (int j = 0; j < 8; ++j) {
      const int idx = j * 256 + tid;
      const int tok = idx >> 5, u = idx & 31;
      float4 a = *(const float4*)(Xg + (size_t)tok * 256 + u * 8);
      float4 b = *(const float4*)(Xg + (size_t)tok * 256 + u * 8 + 4);
      *(short8*)(sm + XU16(tok, u)) = cvt8(a, b);
    }
    __syncthreads();
    floatx4 acc[4][4];   // [token-subtile][ct]
#pragma unroll
    for (int tt = 0; tt < 4; ++tt)
#pragma unroll
      for (int ct = 0; ct < 4; ++ct) for (int r = 0; r < 4; ++r) acc[tt][ct][r] = 0.f;
    const unsigned short* wb = q_wbf + (size_t)(w * 4) * 4096 + lnn * 8;
#pragma unroll
    for (int kc = 0; kc < 8; ++kc) {
      short8 wf[4];
#pragma unroll
      for (int ct = 0; ct < 4; ++ct) wf[ct] = *(const short8*)(wb + (ct * 8 + kc) * 512);
#pragma unroll
      for (int tt = 0; tt < 4; ++tt) {
        short8 xf = *(const short8*)(sm + XU16(tt * 16 + l15, kc * 4 + qd));
#pragma unroll
        for (int ct = 0; ct < 4; ++ct)
          acc[tt][ct] = __builtin_amdgcn_mfma_f32_16x16x32_bf16(wf[ct], xf, acc[tt][ct], 0, 0, 0);
      }
    }
    const int chb = w * 64;
#pragma unroll
    for (int tt = 0; tt < 4; ++tt) {
      const int tok = (int)tok0 + tt * 16 + l15;
      const int b = tok >> 12, trow = tok & 4095;
#pragma unroll
      for (int ct = 0; ct < 4; ++ct) {
        const int ch = chb + ct * 16 + qd * 4;
        float4 bb = *(const float4*)&q_b[ch];
        uint2 u;
        u.x = pk_bf16(acc[tt][ct][0] + bb.x * QSCALE, acc[tt][ct][1] + bb.y * QSCALE);
        u.y = pk_bf16(acc[tt][ct][2] + bb.z * QSCALE, acc[tt][ct][3] + bb.w * QSCALE);
        const int h = ch >> 5, d0 = ch & 31;
        *(uint2*)&qbf[((size_t)(b * HEADS + h) * NN + trow) * HD + d0] = u;
      }
    }
    return;
  }

  // ---------------- conv + LN + KV tile: 32 kv tokens (one kv row) ----------
  unsigned short* xs = sm + 33024;
  const int gt0 = blockIdx.x * 32;
  const int b = gt0 >> 10, tl = gt0 & 1023;
  const int ti = tl >> 5;               // kv row (full row per block)
  // coalesced patch staging: 128 x-tokens (2 rows x 64 cols) x 256 ch fp32.
  // dst feature f = q*256 + c (quadrant-major), q = di*2 + dj; tk = col>>1.
#pragma unroll
  for (int it = 0; it < 16; ++it) {
    const int g = it * 256 + tid;     // 0..4095 16B-units
    const int xt = g >> 5, u = g & 31;
    const int di = xt >> 6, xc = xt & 63;
    const int row = (2 * ti + di) * 64 + xc;
    const float* s = &x[((size_t)b * NN + row) * CCH + u * 8];
    float4 a = *(const float4*)s;
    float4 b2 = *(const float4*)(s + 4);
    const int tk = xc >> 1, q = di * 2 + (xc & 1);
    *(short8*)(sm + (tk * 129 + q * 32 + u) * 8) = cvt8(a, b2);
  }
  __syncthreads();
  floatx4 acc[2][4];   // [token-group][ct]
#pragma unroll
  for (int tg = 0; tg < 2; ++tg)
#pragma unroll
    for (int ct = 0; ct < 4; ++ct) for (int r = 0; r < 4; ++r) acc[tg][ct][r] = 0.f;
  const unsigned short* wbc = sr_wbf + lnn * 8;
#pragma unroll
  for (int kc = 0; kc < 32; ++kc) {
    short8 xf0 = *(const short8*)(sm + (l15 * 129 + kc * 4 + qd) * 8);
    short8 xf1 = *(const short8*)(sm + ((16 + l15) * 129 + kc * 4 + qd) * 8);
#pragma unroll
    for (int ct = 0; ct < 4; ++ct) {
      short8 wf = *(const short8*)(wbc + ((size_t)((w * 4 + ct) * 32 + kc)) * 512);
      acc[0][ct] = __builtin_amdgcn_mfma_f32_16x16x32_bf16(wf, xf0, acc[0][ct], 0, 0, 0);
      acc[1][ct] = __builtin_amdgcn_mfma_f32_16x16x32_bf16(wf, xf1, acc[1][ct], 0, 0, 0);
    }
  }
  __syncthreads();
  float* ft = (float*)sm;    // 32 tok x 260 f32 (aliases dead patch region)
#pragma unroll
  for (int tg = 0; tg < 2; ++tg)
#pragma unroll
    for (int ct = 0; ct < 4; ++ct) {
      float4 o;
      o.x = acc[tg][ct][0]; o.y = acc[tg][ct][1]; o.z = acc[tg][ct][2]; o.w = acc[tg][ct][3];
      *(float4*)&ft[(tg * 16 + l15) * 260 + w * 64 + ct * 16 + qd * 4] = o;
    }
  __syncthreads();
#pragma unroll 1
  for (int m2 = 0; m2 < 2; ++m2) {
    const int tk = m2 * 16 + (tid >> 4), l16 = tid & 15;
    float v[16];
    float4* vv = (float4*)v;
#pragma unroll
    for (int m = 0; m < 4; ++m) {
      float4 t = *(float4*)&ft[tk * 260 + l16 * 16 + m * 4];
      float4 sb = *(const float4*)&sr_b[l16 * 16 + m * 4];
      t.x += sb.x; t.y += sb.y; t.z += sb.z; t.w += sb.w;
      vv[m] = t;
    }
    float s1 = 0.f, s2 = 0.f;
#pragma unroll
    for (int i = 0; i < 16; ++i) { s1 += v[i]; s2 += v[i] * v[i]; }
#pragma unroll
    for (int off = 1; off < 16; off <<= 1) {
      s1 += __shfl_xor(s1, off);
      s2 += __shfl_xor(s2, off);
    }
    const float mu = s1 * (1.f / 256.f);
    const float rstd = rsqrtf(s2 * (1.f / 256.f) - mu * mu + EPS_LN);
#pragma unroll
    for (int m = 0; m < 2; ++m) {
      float4 ga = *(const float4*)&ln_g[l16 * 16 + m * 8];
      float4 gb = *(const float4*)&ln_g[l16 * 16 + m * 8 + 4];
      float4 ba = *(const float4*)&ln_b[l16 * 16 + m * 8];
      float4 bb = *(const float4*)&ln_b[l16 * 16 + m * 8 + 4];
      float4 oa, ob;
      oa.x = (vv[m * 2].x - mu) * rstd * ga.x + ba.x;
      oa.y = (vv[m * 2].y - mu) * rstd * ga.y + ba.y;
      oa.z = (vv[m * 2].z - mu) * rstd * ga.z + ba.z;
      oa.w = (vv[m * 2].w - mu) * rstd * ga.w + ba.w;
      ob.x = (vv[m * 2 + 1].x - mu) * rstd * gb.x + bb.x;
      ob.y = (vv[m * 2 + 1].y - mu) * rstd * gb.y + bb.y;
      ob.z = (vv[m * 2 + 1].z - mu) * rstd * gb.z + bb.z;
      ob.w = (vv[m * 2 + 1].w - mu) * rstd * gb.w + bb.w;
      *(short8*)(xs + XU16(tk, l16 * 2 + m)) = cvt8(oa, ob);
    }
  }
  __syncthreads();
  const bool isV = (w >= 2);
  const int chb = w * 128;
  floatx4 kacc[2][8];   // [token-group][ct]
#pragma unroll
  for (int tg = 0; tg < 2; ++tg)
#pragma unroll
    for (int ct = 0; ct < 8; ++ct) for (int r = 0; r < 4; ++r) kacc[tg][ct][r] = 0.f;
  const unsigned short* wb = kv_wbf + (size_t)(chb >> 4) * 4096 + lnn * 8;
  if (!isV) {
#pragma unroll
    for (int kc = 0; kc < 8; ++kc) {
      short8 xf0 = *(const short8*)(xs + XU16(l15, kc * 4 + qd));
      short8 xf1 = *(const short8*)(xs + XU16(16 + l15, kc * 4 + qd));
#pragma unroll
      for (int ct = 0; ct < 8; ++ct) {
        short8 wf = *(const short8*)(wb + (ct * 8 + kc) * 512);
        kacc[0][ct] = __builtin_amdgcn_mfma_f32_16x16x32_bf16(wf, xf0, kacc[0][ct], 0, 0, 0);
        kacc[1][ct] = __builtin_amdgcn_mfma_f32_16x16x32_bf16(wf, xf1, kacc[1][ct], 0, 0, 0);
      }
    }
#pragma unroll
    for (int tg = 0; tg < 2; ++tg) {
      const int tok = tl + tg * 16 + l15;
#pragma unroll
      for (int ct = 0; ct < 8; ++ct) {
        const int ch = chb + ct * 16 + qd * 4;
        float4 bb = *(const float4*)&kv_b[ch];
        uint2 u;
        u.x = pk_bf16(kacc[tg][ct][0] + bb.x, kacc[tg][ct][1] + bb.y);
        u.y = pk_bf16(kacc[tg][ct][2] + bb.z, kacc[tg][ct][3] + bb.w);
        const int h = ch >> 5, d0 = ch & 31;
        *(uint2*)&kbf[((size_t)(b * HEADS + h) * NKV + tok) * HD + d0] = u;
      }
    }
  } else {
#pragma unroll
    for (int kc = 0; kc < 8; ++kc) {
      short8 xf0 = *(const short8*)(xs + XU16(l15, kc * 4 + qd));
      short8 xf1 = *(const short8*)(xs + XU16(16 + l15, kc * 4 + qd));
#pragma unroll
      for (int ct = 0; ct < 8; ++ct) {
        short8 wf = *(const short8*)(wb + (ct * 8 + kc) * 512);
        kacc[0][ct] = __builtin_amdgcn_mfma_f32_16x16x32_bf16(xf0, wf, kacc[0][ct], 0, 0, 0);
        kacc[1][ct] = __builtin_amdgcn_mfma_f32_16x16x32_bf16(xf1, wf, kacc[1][ct], 0, 0, 0);
      }
    }
    // frag-major V store: per tg, tokens (tl+tg*16) + qd*4 + r, lane l15 -> ch
#pragma unroll
    for (int tg = 0; tg < 2; ++tg) {
      const int tb = tl + tg * 16;
      const int ccv = tb >> 6;
      const int base6 = (tb & 63) + qd * 4;
      const int kg = (base6 >> 5) & 1, kq = (base6 >> 3) & 3, j0 = base6 & 7;
#pragma unroll
      for (int ct = 0; ct < 8; ++ct) {
        const int vc = chb - 256 + ct * 16 + l15;
        const float bb = kv_b[vc + 256];
        uint2 u;
        u.x = pk_bf16(kacc[tg][ct][0] + bb, kacc[tg][ct][1] + bb);
        u.y = pk_bf16(kacc[tg][ct][2] + bb, kacc[tg][ct][3] + bb);
        const int hh = vc >> 5, d = vc & 31;
        const int half = d >> 4, dl = d & 15;
        const int unit = ((ccv * 2 + kg) * 2 + half) * 64 + kq * 16 + dl;
        *(uint2*)&vtbf[(size_t)(b * HEADS + hh) * 32768 + unit * 8 + j0] = u;
      }
    }
  }
}

// ---------------------------------------------------------------------------
// FUSED flash attention + output projection (identical to R3 -- control).
// Block = 512 thr (8 waves) owns 64 tokens x ALL 8 heads; wave = head.
// ---------------------------------------------------------------------------
__global__ __launch_bounds__(512) void attn_proj(
    const unsigned short* __restrict__ qbf,
    const unsigned short* __restrict__ kbf,
    const unsigned short* __restrict__ vtbf,
    const unsigned short* __restrict__ p_wbf, const float* __restrict__ p_b,
    float* __restrict__ out) {
  __shared__ unsigned short sm[34816];
  const int tid = threadIdx.x, w = tid >> 6, ln = tid & 63;
  const int l15 = ln & 15, qd = ln >> 4;
  const int g0 = blockIdx.x * 64;
  const int b = g0 >> 12, trow0 = g0 & 4095;
  const int bh = b * HEADS + w;
  const unsigned short* kbase = kbf + (size_t)bh * NKV * HD;
  const unsigned short* vfb = vtbf + (size_t)bh * 32768;
  const int q0 = trow0 + l15;
  short8 qf[4];
#pragma unroll
  for (int qt = 0; qt < 4; ++qt)
    qf[qt] = *(const short8*)(qbf + ((size_t)bh * NN + q0 + qt * 16) * HD + qd * 8);
  const short8 ones = {16256, 16256, 16256, 16256, 16256, 16256, 16256, 16256};
  floatx4 a0[4], a1[4], al[4];
#pragma unroll
  for (int qt = 0; qt < 4; ++qt)
#pragma unroll
    for (int r = 0; r < 4; ++r) { a0[qt][r] = 0.f; a1[qt][r] = 0.f; al[qt][r] = 0.f; }
  const int pu = w * 544;

  short8 kfA[4], vA[4], kfB[4], vB[4];
#define LOADKV(KF, VV, CC) do {                                               \
    const unsigned short* kp = kbase + ((size_t)(CC) * 64 + l15) * HD + qd * 8; \
    _Pragma("unroll")                                                          \
    for (int t = 0; t < 4; ++t) (KF)[t] = *(const short8*)(kp + t * 16 * HD);  \
    const unsigned short* vp = vfb + ((size_t)(CC) * 256 + ln) * 8;            \
    _Pragma("unroll")                                                          \
    for (int u = 0; u < 4; ++u) (VV)[u] = *(const short8*)(vp + u * 512);      \
  } while (0)

#define CHUNK(KF, VV) do {                                                     \
    _Pragma("unroll")                                                          \
    for (int qt = 0; qt < 4; ++qt) {                                           \
      const int pq = pu + qt * 136;                                            \
      floatx4 s[4];                                                            \
      _Pragma("unroll")                                                        \
      for (int t = 0; t < 4; ++t) {                                            \
        floatx4 z; for (int r = 0; r < 4; ++r) z[r] = 0.f;                     \
        s[t] = __builtin_amdgcn_mfma_f32_16x16x32_bf16((KF)[t], qf[qt], z, 0, 0, 0); \
      }                                                                        \
      _Pragma("unroll")                                                        \
      for (int t = 0; t < 4; ++t) {                                            \
        uint2 pk;                                                              \
        pk.x = pk_bf16(__builtin_amdgcn_exp2f(s[t][0]), __builtin_amdgcn_exp2f(s[t][1])); \
        pk.y = pk_bf16(__builtin_amdgcn_exp2f(s[t][2]), __builtin_amdgcn_exp2f(s[t][3])); \
        const int unit = pq + (t >> 1) * 68 + ((t & 1) * 2 + (qd >> 1)) * 16 + l15; \
        *(uint2*)(sm + unit * 8 + (qd & 1) * 4) = pk;                          \
      }                                                                        \
      _Pragma("unroll")                                                        \
      for (int kg = 0; kg < 2; ++kg) {                                         \
        short8 pf = *(const short8*)(sm + (pq + kg * 68 + ln) * 8);            \
        a0[qt] = __builtin_amdgcn_mfma_f32_16x16x32_bf16((VV)[kg * 2], pf, a0[qt], 0, 0, 0);     \
        a1[qt] = __builtin_amdgcn_mfma_f32_16x16x32_bf16((VV)[kg * 2 + 1], pf, a1[qt], 0, 0, 0); \
        al[qt] = __builtin_amdgcn_mfma_f32_16x16x32_bf16(ones, pf, al[qt], 0, 0, 0);             \
      }                                                                        \
    }                                                                          \
  } while (0)

  LOADKV(kfA, vA, 0);
  for (int cc = 0; cc < 16; cc += 2) {
    LOADKV(kfB, vB, cc + 1);
    CHUNK(kfA, vA);
    if (cc + 2 < 16) LOADKV(kfA, vA, cc + 2);
    CHUNK(kfB, vB);
  }
#undef LOADKV
#undef CHUNK

  __syncthreads();
#pragma unroll
  for (int qt = 0; qt < 4; ++qt) {
    const float inv = 1.f / al[qt][0];
    const int t = qt * 16 + l15;
    const int u0 = w * 4 + (qd >> 1);
    uint2 v0, v1;
    v0.x = pk_bf16(a0[qt][0] * inv, a0[qt][1] * inv);
    v0.y = pk_bf16(a0[qt][2] * inv, a0[qt][3] * inv);
    v1.x = pk_bf16(a1[qt][0] * inv, a1[qt][1] * inv);
    v1.y = pk_bf16(a1[qt][2] * inv, a1[qt][3] * inv);
    *(uint2*)(sm + XU16(t, u0) + (qd & 1) * 4) = v0;
    *(uint2*)(sm + XU16(t, u0 + 2) + (qd & 1) * 4) = v1;
  }
  __syncthreads();

  const int cb = w & 3, th = w >> 2;
  floatx4 pacc[2][4];
#pragma unroll
  for (int tt = 0; tt < 2; ++tt)
#pragma unroll
    for (int ct = 0; ct < 4; ++ct) for (int r = 0; r < 4; ++r) pacc[tt][ct][r] = 0.f;
  const unsigned short* wb = p_wbf + (size_t)(cb * 4) * 4096 + ln * 8;
#pragma unroll
  for (int kc = 0; kc < 8; ++kc) {
    short8 wf[4];
#pragma unroll
    for (int ct = 0; ct < 4; ++ct) wf[ct] = *(const short8*)(wb + (ct * 8 + kc) * 512);
#pragma unroll
    for (int tt = 0; tt < 2; ++tt) {
      short8 xf = *(const short8*)(sm + XU16(th * 32 + tt * 16 + l15, kc * 4 + qd));
#pragma unroll
      for (int ct = 0; ct < 4; ++ct)
        pacc[tt][ct] = __builtin_amdgcn_mfma_f32_16x16x32_bf16(wf[ct], xf, pacc[tt][ct], 0, 0, 0);
    }
  }
  const int chb = cb * 64;
#pragma unroll
  for (int tt = 0; tt < 2; ++tt) {
    const long tok = (long)g0 + th * 32 + tt * 16 + l15;
#pragma unroll
    for (int ct = 0; ct < 4; ++ct) {
      const int ch = chb + ct * 16 + qd * 4;
      float4 bb = *(const float4*)&p_b[ch];
      float4 o;
      o.x = pacc[tt][ct][0] + bb.x; o.y = pacc[tt][ct][1] + bb.y;
      o.z = pacc[tt][ct][2] + bb.z; o.w = pacc[tt][ct][3] + bb.w;
      *(float4*)&out[(size_t)tok * 256 + ch] = o;
    }
  }
}

// ---------------------------------------------------------------------------
extern "C" void kernel_launch(void* const* d_in, const int* in_sizes, int n_in,
                              void* d_out, int out_size, void* d_ws, size_t ws_size,
                              hipStream_t stream) {
  const float* x      = (const float*)d_in[0];
  const float* q_w    = (const float*)d_in[1];
  const float* q_b    = (const float*)d_in[2];
  const float* kv_w   = (const float*)d_in[3];
  const float* kv_b   = (const float*)d_in[4];
  const float* sr_w   = (const float*)d_in[5];
  const float* sr_b   = (const float*)d_in[6];
  const float* ln_g   = (const float*)d_in[7];
  const float* ln_b   = (const float*)d_in[8];
  const float* proj_w = (const float*)d_in[9];
  const float* proj_b = (const float*)d_in[10];
  float* out = (float*)d_out;

  char* base = (char*)d_ws;
  const size_t MB = 1048576;
  unsigned short* q_wbf    = (unsigned short*)(base);                 // 128 KB
  unsigned short* kv_wbf   = (unsigned short*)(base + 131072);        // 256 KB
  unsigned short* sr_wbf   = (unsigned short*)(base + 393216);        // 512 KB
  unsigned short* proj_wbf = (unsigned short*)(base + 917504);        // 128 KB
  unsigned short* q_bf     = (unsigned short*)(base + 1 * MB);        // 8 MB
  unsigned short* k_bf     = (unsigned short*)(base + 9 * MB);        // 2 MB
  unsigned short* vt_bf    = (unsigned short*)(base + 11 * MB);       // 2 MB

  cast_weights<<<256, 256, 0, stream>>>(q_w, kv_w, sr_w, proj_w,
                                        q_wbf, kv_wbf, sr_wbf, proj_wbf);
  qconv_gemm<<<384, 256, 0, stream>>>(x, q_wbf, q_b, sr_wbf, sr_b, ln_g, ln_b,
                                      kv_wbf, kv_b, q_bf, k_bf, vt_bf);
  attn_proj<<<256, 512, 0, stream>>>(q_bf, k_bf, vt_bf, proj_wbf, proj_b, out);
}

// Round 6
// 147.203 us; speedup vs baseline: 1.3945x; 1.1103x over previous
//
#include <hip/hip_runtime.h>
#include <hip/hip_bf16.h>
#include <math.h>

#define BB 4
#define NN 4096
#define CCH 256
#define HEADS 8
#define HD 32
#define NKV 1024
#define EPS_LN 1e-5f

typedef short short8 __attribute__((ext_vector_type(8)));
typedef float floatx4 __attribute__((ext_vector_type(4)));

// scale = HD^-0.5 folded with log2(e): softmax runs in exp2 domain
#define QSCALE (0.17677669529663687f * 1.4426950408889634f)

__device__ __forceinline__ unsigned pk_bf16(float a, float b) {
  __hip_bfloat162 h = __float22bfloat162_rn(make_float2(a, b));
  unsigned u; __builtin_memcpy(&u, &h, 4); return u;
}

__device__ __forceinline__ short8 cvt8(float4 a, float4 b) {
  union { short8 s; unsigned u[4]; } r;
  r.u[0] = pk_bf16(a.x, a.y); r.u[1] = pk_bf16(a.z, a.w);
  r.u[2] = pk_bf16(b.x, b.y); r.u[3] = pk_bf16(b.z, b.w);
  return r.s;
}

// ---------------------------------------------------------------------------
// Cast weights fp32 -> bf16, FRAGMENT-MAJOR swizzle:
// unit(row,col) = ((row>>4)*(Kd/32) + (col>>5))*64 + ((col>>3)&3)*16 + (row&15)
// -> a wave's wf load is one contiguous 1KB segment. QSCALE folded into q_w.
// sr_w additionally gets K permuted to QUADRANT-MAJOR: col' = q*256 + c.
// ---------------------------------------------------------------------------
__global__ __launch_bounds__(256) void cast_weights(
    const float* __restrict__ q_w, const float* __restrict__ kv_w,
    const float* __restrict__ sr_w, const float* __restrict__ proj_w,
    unsigned short* __restrict__ q_wbf, unsigned short* __restrict__ kv_wbf,
    unsigned short* __restrict__ sr_wbf, unsigned short* __restrict__ proj_wbf) {
  const int e = (blockIdx.x * 256 + threadIdx.x) * 8;
  if (e >= 196608 && e < 458752) {
    // sr_w: 8 consecutive src elems = (row, c0..c0+1, q0..3), c0 even
    const int off = e - 196608;
    const int row = off >> 10;
    const int wr = off & 1023;
    const int c0 = (wr >> 3) * 2;
    float4 a = *(const float4*)&sr_w[off];
    float4 b = *(const float4*)&sr_w[off + 4];
    const float v[8] = {a.x, a.y, a.z, a.w, b.x, b.y, b.z, b.w};
    const int base = (row >> 4) * 32;   // Kd/32 = 32
#pragma unroll
    for (int q = 0; q < 4; ++q) {
      const int unit = (base + q * 8 + (c0 >> 5)) * 64 + ((c0 >> 3) & 3) * 16 + (row & 15);
      *(unsigned*)&sr_wbf[unit * 8 + (c0 & 7)] = pk_bf16(v[q], v[4 + q]);
    }
    return;
  }
  const float* src; unsigned short* dst; int off; float sc = 1.f;
  if (e < 65536)       { src = q_w;    dst = q_wbf;    off = e;          sc = QSCALE; }
  else if (e < 196608) { src = kv_w;   dst = kv_wbf;   off = e - 65536; }
  else                 { src = proj_w; dst = proj_wbf; off = e - 458752; }
  const int row = off >> 8;
  const int col = off & 255;
  const int unit = ((row >> 4) * 8 + (col >> 5)) * 64 + ((col >> 3) & 3) * 16 + (row & 15);
  float4 a = *(const float4*)&src[off];
  float4 b = *(const float4*)&src[off + 4];
  a.x *= sc; a.y *= sc; a.z *= sc; a.w *= sc;
  b.x *= sc; b.y *= sc; b.z *= sc; b.w *= sc;
  *(short8*)&dst[unit * 8] = cvt8(a, b);
}

// X-tile LDS layout (tokens x 32 16B-units, 33-unit skew)
#define XU16(t, u) (((t) * 33 + (u)) * 8)

// ---------------------------------------------------------------------------
// Fused (SR-conv + LN + KV-projection) + Q-projection.
// Grid 512 x 256 thr: bx < 256 -> conv tile (16 kv tok, R3-identical);
// bx >= 256 -> Q tile (64 tok: staging 33.8 KB fits the SAME 41.5 KB LDS as
// the conv branch -> occupancy unchanged (3 blk/CU), q_wbf L2 traffic halved
// vs R3, each weight fragment feeds 4 MFMAs).
// LESSON (R5): LDS is allocated per-kernel, not per-branch -- amortization
// must never grow the shared static buffer.
// ---------------------------------------------------------------------------
__global__ __launch_bounds__(256) void qconv_gemm(const float* __restrict__ x,
    const unsigned short* __restrict__ q_wbf, const float* __restrict__ q_b,
    const unsigned short* __restrict__ sr_wbf, const float* __restrict__ sr_b,
    const float* __restrict__ ln_g, const float* __restrict__ ln_b,
    const unsigned short* __restrict__ kv_wbf, const float* __restrict__ kv_b,
    unsigned short* __restrict__ qbf,
    unsigned short* __restrict__ kbf, unsigned short* __restrict__ vtbf) {
  __shared__ unsigned short sm[20736];
  const int tid = threadIdx.x, w = tid >> 6, lnn = tid & 63;
  const int l15 = lnn & 15, qd = lnn >> 4;

  if (blockIdx.x >= 256) {
    // ---------------- Q projection tile: 64 tokens ----------------
    const long tok0 = (long)(blockIdx.x - 256) * 64;
    const float* Xg = x + tok0 * 256;
#pragma unroll
    for (int j = 0; j < 8; ++j) {
      const int idx = j * 256 + tid;
      const int tok = idx >> 5, u = idx & 31;
      float4 a = *(const float4*)(Xg + (size_t)tok * 256 + u * 8);
      float4 b = *(const float4*)(Xg + (size_t)tok * 256 + u * 8 + 4);
      *(short8*)(sm + XU16(tok, u)) = cvt8(a, b);
    }
    __syncthreads();
    floatx4 acc[4][4];   // [token-subtile][ct]
#pragma unroll
    for (int tt = 0; tt < 4; ++tt)
#pragma unroll
      for (int ct = 0; ct < 4; ++ct) for (int r = 0; r < 4; ++r) acc[tt][ct][r] = 0.f;
    const unsigned short* wb = q_wbf + (size_t)(w * 4) * 4096 + lnn * 8;
#pragma unroll
    for (int kc = 0; kc < 8; ++kc) {
      short8 wf[4];
#pragma unroll
      for (int ct = 0; ct < 4; ++ct) wf[ct] = *(const short8*)(wb + (ct * 8 + kc) * 512);
#pragma unroll
      for (int tt = 0; tt < 4; ++tt) {
        short8 xf = *(const short8*)(sm + XU16(tt * 16 + l15, kc * 4 + qd));
#pragma unroll
        for (int ct = 0; ct < 4; ++ct)
          acc[tt][ct] = __builtin_amdgcn_mfma_f32_16x16x32_bf16(wf[ct], xf, acc[tt][ct], 0, 0, 0);
      }
    }
    const int chb = w * 64;
#pragma unroll
    for (int tt = 0; tt < 4; ++tt) {
      const int tok = (int)tok0 + tt * 16 + l15;
      const int b = tok >> 12, trow = tok & 4095;
#pragma unroll
      for (int ct = 0; ct < 4; ++ct) {
        const int ch = chb + ct * 16 + qd * 4;
        float4 bb = *(const float4*)&q_b[ch];
        uint2 u;
        u.x = pk_bf16(acc[tt][ct][0] + bb.x * QSCALE, acc[tt][ct][1] + bb.y * QSCALE);
        u.y = pk_bf16(acc[tt][ct][2] + bb.z * QSCALE, acc[tt][ct][3] + bb.w * QSCALE);
        const int h = ch >> 5, d0 = ch & 31;
        *(uint2*)&qbf[((size_t)(b * HEADS + h) * NN + trow) * HD + d0] = u;
      }
    }
    return;
  }

  // ---------------- conv + LN + KV tile (R3-identical) ----------------
  unsigned short* xs = sm + 16512;
  const int gt0 = blockIdx.x * 16;
  const int b = gt0 >> 10, tl = gt0 & 1023;
  const int ti = (tl & 1023) >> 5;
  const int cbase = 2 * (tl & 31);
  // coalesced patch staging: 64 x-tokens (2 rows x 32 cols) x 256 ch fp32.
  // dst feature f = q*256 + c (quadrant-major), q = di*2 + dj.
#pragma unroll
  for (int it = 0; it < 8; ++it) {
    const int g = it * 256 + tid;     // 0..2047 16B-units
    const int xt = g >> 5, u = g & 31;
    const int di = xt >> 5, cj = xt & 31;
    const int row = (2 * ti + di) * 64 + cbase + cj;
    const float* s = &x[((size_t)b * NN + row) * CCH + u * 8];
    float4 a = *(const float4*)s;
    float4 b2 = *(const float4*)(s + 4);
    const int tk = cj >> 1, q = di * 2 + (cj & 1);
    *(short8*)(sm + (tk * 129 + q * 32 + u) * 8) = cvt8(a, b2);
  }
  __syncthreads();
  floatx4 acc[4];
#pragma unroll
  for (int ct = 0; ct < 4; ++ct) for (int r = 0; r < 4; ++r) acc[ct][r] = 0.f;
  const unsigned short* wbc = sr_wbf + lnn * 8;
#pragma unroll
  for (int kc = 0; kc < 32; ++kc) {
    short8 xf = *(const short8*)(sm + (l15 * 129 + kc * 4 + qd) * 8);
#pragma unroll
    for (int ct = 0; ct < 4; ++ct) {
      short8 wf = *(const short8*)(wbc + ((w * 4 + ct) * 32 + kc) * 512);
      acc[ct] = __builtin_amdgcn_mfma_f32_16x16x32_bf16(wf, xf, acc[ct], 0, 0, 0);
    }
  }
  __syncthreads();
  float* ft = (float*)sm;
#pragma unroll
  for (int ct = 0; ct < 4; ++ct) {
    float4 o;
    o.x = acc[ct][0]; o.y = acc[ct][1]; o.z = acc[ct][2]; o.w = acc[ct][3];
    *(float4*)&ft[l15 * 260 + w * 64 + ct * 16 + qd * 4] = o;
  }
  __syncthreads();
  {
    const int tk = tid >> 4, l16 = tid & 15;
    float v[16];
    float4* vv = (float4*)v;
#pragma unroll
    for (int m = 0; m < 4; ++m) {
      float4 t = *(float4*)&ft[tk * 260 + l16 * 16 + m * 4];
      float4 sb = *(const float4*)&sr_b[l16 * 16 + m * 4];
      t.x += sb.x; t.y += sb.y; t.z += sb.z; t.w += sb.w;
      vv[m] = t;
    }
    float s1 = 0.f, s2 = 0.f;
#pragma unroll
    for (int i = 0; i < 16; ++i) { s1 += v[i]; s2 += v[i] * v[i]; }
#pragma unroll
    for (int off = 1; off < 16; off <<= 1) {
      s1 += __shfl_xor(s1, off);
      s2 += __shfl_xor(s2, off);
    }
    const float mu = s1 * (1.f / 256.f);
    const float rstd = rsqrtf(s2 * (1.f / 256.f) - mu * mu + EPS_LN);
#pragma unroll
    for (int m = 0; m < 2; ++m) {
      float4 ga = *(const float4*)&ln_g[l16 * 16 + m * 8];
      float4 gb = *(const float4*)&ln_g[l16 * 16 + m * 8 + 4];
      float4 ba = *(const float4*)&ln_b[l16 * 16 + m * 8];
      float4 bb = *(const float4*)&ln_b[l16 * 16 + m * 8 + 4];
      float4 oa, ob;
      oa.x = (vv[m * 2].x - mu) * rstd * ga.x + ba.x;
      oa.y = (vv[m * 2].y - mu) * rstd * ga.y + ba.y;
      oa.z = (vv[m * 2].z - mu) * rstd * ga.z + ba.z;
      oa.w = (vv[m * 2].w - mu) * rstd * ga.w + ba.w;
      ob.x = (vv[m * 2 + 1].x - mu) * rstd * gb.x + bb.x;
      ob.y = (vv[m * 2 + 1].y - mu) * rstd * gb.y + bb.y;
      ob.z = (vv[m * 2 + 1].z - mu) * rstd * gb.z + bb.z;
      ob.w = (vv[m * 2 + 1].w - mu) * rstd * gb.w + bb.w;
      *(short8*)(xs + XU16(tk, l16 * 2 + m)) = cvt8(oa, ob);
    }
  }
  __syncthreads();
  const bool isV = (w >= 2);
  const int chb = w * 128;
  floatx4 kacc[8];
#pragma unroll
  for (int ct = 0; ct < 8; ++ct) for (int r = 0; r < 4; ++r) kacc[ct][r] = 0.f;
  const unsigned short* wb = kv_wbf + (size_t)(chb >> 4) * 4096 + lnn * 8;
  if (!isV) {
#pragma unroll
    for (int kc = 0; kc < 8; ++kc) {
      short8 xf = *(const short8*)(xs + XU16(l15, kc * 4 + qd));
#pragma unroll
      for (int ct = 0; ct < 8; ++ct) {
        short8 wf = *(const short8*)(wb + (ct * 8 + kc) * 512);
        kacc[ct] = __builtin_amdgcn_mfma_f32_16x16x32_bf16(wf, xf, kacc[ct], 0, 0, 0);
      }
    }
    const int tok = tl + l15;
#pragma unroll
    for (int ct = 0; ct < 8; ++ct) {
      const int ch = chb + ct * 16 + qd * 4;
      float4 bb = *(const float4*)&kv_b[ch];
      uint2 u;
      u.x = pk_bf16(kacc[ct][0] + bb.x, kacc[ct][1] + bb.y);
      u.y = pk_bf16(kacc[ct][2] + bb.z, kacc[ct][3] + bb.w);
      const int h = ch >> 5, d0 = ch & 31;
      *(uint2*)&kbf[((size_t)(b * HEADS + h) * NKV + tok) * HD + d0] = u;
    }
  } else {
#pragma unroll
    for (int kc = 0; kc < 8; ++kc) {
      short8 xf = *(const short8*)(xs + XU16(l15, kc * 4 + qd));
#pragma unroll
      for (int ct = 0; ct < 8; ++ct) {
        short8 wf = *(const short8*)(wb + (ct * 8 + kc) * 512);
        kacc[ct] = __builtin_amdgcn_mfma_f32_16x16x32_bf16(xf, wf, kacc[ct], 0, 0, 0);
      }
    }
    // frag-major V store: tokens tl + qd*4 + r, lane l15 -> channel
    const int ccv = tl >> 6;
    const int base6 = (tl & 63) + qd * 4;
    const int kg = (base6 >> 5) & 1, kq = (base6 >> 3) & 3, j0 = base6 & 7;
#pragma unroll
    for (int ct = 0; ct < 8; ++ct) {
      const int vc = chb - 256 + ct * 16 + l15;
      const float bb = kv_b[vc + 256];
      uint2 u;
      u.x = pk_bf16(kacc[ct][0] + bb, kacc[ct][1] + bb);
      u.y = pk_bf16(kacc[ct][2] + bb, kacc[ct][3] + bb);
      const int hh = vc >> 5, d = vc & 31;
      const int half = d >> 4, dl = d & 15;
      const int unit = ((ccv * 2 + kg) * 2 + half) * 64 + kq * 16 + dl;
      *(uint2*)&vtbf[(size_t)(b * HEADS + hh) * 32768 + unit * 8 + j0] = u;
    }
  }
}

// ---------------------------------------------------------------------------
// FUSED flash attention + output projection (identical to R3 -- control).
// Block = 512 thr (8 waves) owns 64 tokens x ALL 8 heads; wave = head.
// ---------------------------------------------------------------------------
__global__ __launch_bounds__(512) void attn_proj(
    const unsigned short* __restrict__ qbf,
    const unsigned short* __restrict__ kbf,
    const unsigned short* __restrict__ vtbf,
    const unsigned short* __restrict__ p_wbf, const float* __restrict__ p_b,
    float* __restrict__ out) {
  __shared__ unsigned short sm[34816];
  const int tid = threadIdx.x, w = tid >> 6, ln = tid & 63;
  const int l15 = ln & 15, qd = ln >> 4;
  const int g0 = blockIdx.x * 64;
  const int b = g0 >> 12, trow0 = g0 & 4095;
  const int bh = b * HEADS + w;
  const unsigned short* kbase = kbf + (size_t)bh * NKV * HD;
  const unsigned short* vfb = vtbf + (size_t)bh * 32768;
  const int q0 = trow0 + l15;
  short8 qf[4];
#pragma unroll
  for (int qt = 0; qt < 4; ++qt)
    qf[qt] = *(const short8*)(qbf + ((size_t)bh * NN + q0 + qt * 16) * HD + qd * 8);
  const short8 ones = {16256, 16256, 16256, 16256, 16256, 16256, 16256, 16256};
  floatx4 a0[4], a1[4], al[4];
#pragma unroll
  for (int qt = 0; qt < 4; ++qt)
#pragma unroll
    for (int r = 0; r < 4; ++r) { a0[qt][r] = 0.f; a1[qt][r] = 0.f; al[qt][r] = 0.f; }
  const int pu = w * 544;

  short8 kfA[4], vA[4], kfB[4], vB[4];
#define LOADKV(KF, VV, CC) do {                                               \
    const unsigned short* kp = kbase + ((size_t)(CC) * 64 + l15) * HD + qd * 8; \
    _Pragma("unroll")                                                          \
    for (int t = 0; t < 4; ++t) (KF)[t] = *(const short8*)(kp + t * 16 * HD);  \
    const unsigned short* vp = vfb + ((size_t)(CC) * 256 + ln) * 8;            \
    _Pragma("unroll")                                                          \
    for (int u = 0; u < 4; ++u) (VV)[u] = *(const short8*)(vp + u * 512);      \
  } while (0)

#define CHUNK(KF, VV) do {                                                     \
    _Pragma("unroll")                                                          \
    for (int qt = 0; qt < 4; ++qt) {                                           \
      const int pq = pu + qt * 136;                                            \
      floatx4 s[4];                                                            \
      _Pragma("unroll")                                                        \
      for (int t = 0; t < 4; ++t) {                                            \
        floatx4 z; for (int r = 0; r < 4; ++r) z[r] = 0.f;                     \
        s[t] = __builtin_amdgcn_mfma_f32_16x16x32_bf16((KF)[t], qf[qt], z, 0, 0, 0); \
      }                                                                        \
      _Pragma("unroll")                                                        \
      for (int t = 0; t < 4; ++t) {                                            \
        uint2 pk;                                                              \
        pk.x = pk_bf16(__builtin_amdgcn_exp2f(s[t][0]), __builtin_amdgcn_exp2f(s[t][1])); \
        pk.y = pk_bf16(__builtin_amdgcn_exp2f(s[t][2]), __builtin_amdgcn_exp2f(s[t][3])); \
        const int unit = pq + (t >> 1) * 68 + ((t & 1) * 2 + (qd >> 1)) * 16 + l15; \
        *(uint2*)(sm + unit * 8 + (qd & 1) * 4) = pk;                          \
      }                                                                        \
      _Pragma("unroll")                                                        \
      for (int kg = 0; kg < 2; ++kg) {                                         \
        short8 pf = *(const short8*)(sm + (pq + kg * 68 + ln) * 8);            \
        a0[qt] = __builtin_amdgcn_mfma_f32_16x16x32_bf16((VV)[kg * 2], pf, a0[qt], 0, 0, 0);     \
        a1[qt] = __builtin_amdgcn_mfma_f32_16x16x32_bf16((VV)[kg * 2 + 1], pf, a1[qt], 0, 0, 0); \
        al[qt] = __builtin_amdgcn_mfma_f32_16x16x32_bf16(ones, pf, al[qt], 0, 0, 0);             \
      }                                                                        \
    }                                                                          \
  } while (0)

  LOADKV(kfA, vA, 0);
  for (int cc = 0; cc < 16; cc += 2) {
    LOADKV(kfB, vB, cc + 1);
    CHUNK(kfA, vA);
    if (cc + 2 < 16) LOADKV(kfA, vA, cc + 2);
    CHUNK(kfB, vB);
  }
#undef LOADKV
#undef CHUNK

  __syncthreads();
#pragma unroll
  for (int qt = 0; qt < 4; ++qt) {
    const float inv = 1.f / al[qt][0];
    const int t = qt * 16 + l15;
    const int u0 = w * 4 + (qd >> 1);
    uint2 v0, v1;
    v0.x = pk_bf16(a0[qt][0] * inv, a0[qt][1] * inv);
    v0.y = pk_bf16(a0[qt][2] * inv, a0[qt][3] * inv);
    v1.x = pk_bf16(a1[qt][0] * inv, a1[qt][1] * inv);
    v1.y = pk_bf16(a1[qt][2] * inv, a1[qt][3] * inv);
    *(uint2*)(sm + XU16(t, u0) + (qd & 1) * 4) = v0;
    *(uint2*)(sm + XU16(t, u0 + 2) + (qd & 1) * 4) = v1;
  }
  __syncthreads();

  const int cb = w & 3, th = w >> 2;
  floatx4 pacc[2][4];
#pragma unroll
  for (int tt = 0; tt < 2; ++tt)
#pragma unroll
    for (int ct = 0; ct < 4; ++ct) for (int r = 0; r < 4; ++r) pacc[tt][ct][r] = 0.f;
  const unsigned short* wb = p_wbf + (size_t)(cb * 4) * 4096 + ln * 8;
#pragma unroll
  for (int kc = 0; kc < 8; ++kc) {
    short8 wf[4];
#pragma unroll
    for (int ct = 0; ct < 4; ++ct) wf[ct] = *(const short8*)(wb + (ct * 8 + kc) * 512);
#pragma unroll
    for (int tt = 0; tt < 2; ++tt) {
      short8 xf = *(const short8*)(sm + XU16(th * 32 + tt * 16 + l15, kc * 4 + qd));
#pragma unroll
      for (int ct = 0; ct < 4; ++ct)
        pacc[tt][ct] = __builtin_amdgcn_mfma_f32_16x16x32_bf16(wf[ct], xf, pacc[tt][ct], 0, 0, 0);
    }
  }
  const int chb = cb * 64;
#pragma unroll
  for (int tt = 0; tt < 2; ++tt) {
    const long tok = (long)g0 + th * 32 + tt * 16 + l15;
#pragma unroll
    for (int ct = 0; ct < 4; ++ct) {
      const int ch = chb + ct * 16 + qd * 4;
      float4 bb = *(const float4*)&p_b[ch];
      float4 o;
      o.x = pacc[tt][ct][0] + bb.x; o.y = pacc[tt][ct][1] + bb.y;
      o.z = pacc[tt][ct][2] + bb.z; o.w = pacc[tt][ct][3] + bb.w;
      *(float4*)&out[(size_t)tok * 256 + ch] = o;
    }
  }
}

// ---------------------------------------------------------------------------
extern "C" void kernel_launch(void* const* d_in, const int* in_sizes, int n_in,
                              void* d_out, int out_size, void* d_ws, size_t ws_size,
                              hipStream_t stream) {
  const float* x      = (const float*)d_in[0];
  const float* q_w    = (const float*)d_in[1];
  const float* q_b    = (const float*)d_in[2];
  const float* kv_w   = (const float*)d_in[3];
  const float* kv_b   = (const float*)d_in[4];
  const float* sr_w   = (const float*)d_in[5];
  const float* sr_b   = (const float*)d_in[6];
  const float* ln_g   = (const float*)d_in[7];
  const float* ln_b   = (const float*)d_in[8];
  const float* proj_w = (const float*)d_in[9];
  const float* proj_b = (const float*)d_in[10];
  float* out = (float*)d_out;

  char* base = (char*)d_ws;
  const size_t MB = 1048576;
  unsigned short* q_wbf    = (unsigned short*)(base);                 // 128 KB
  unsigned short* kv_wbf   = (unsigned short*)(base + 131072);        // 256 KB
  unsigned short* sr_wbf   = (unsigned short*)(base + 393216);        // 512 KB
  unsigned short* proj_wbf = (unsigned short*)(base + 917504);        // 128 KB
  unsigned short* q_bf     = (unsigned short*)(base + 1 * MB);        // 8 MB
  unsigned short* k_bf     = (unsigned short*)(base + 9 * MB);        // 2 MB
  unsigned short* vt_bf    = (unsigned short*)(base + 11 * MB);       // 2 MB

  cast_weights<<<256, 256, 0, stream>>>(q_w, kv_w, sr_w, proj_w,
                                        q_wbf, kv_wbf, sr_wbf, proj_wbf);
  qconv_gemm<<<512, 256, 0, stream>>>(x, q_wbf, q_b, sr_wbf, sr_b, ln_g, ln_b,
                                      kv_wbf, kv_b, q_bf, k_bf, vt_bf);
  attn_proj<<<256, 512, 0, stream>>>(q_bf, k_bf, vt_bf, proj_wbf, proj_b, out);
}

// Round 7
// 140.755 us; speedup vs baseline: 1.4583x; 1.0458x over previous
//
#include <hip/hip_runtime.h>
#include <hip/hip_bf16.h>
#include <math.h>

#define BB 4
#define NN 4096
#define CCH 256
#define HEADS 8
#define HD 32
#define NKV 1024
#define EPS_LN 1e-5f

typedef short short8 __attribute__((ext_vector_type(8)));
typedef float floatx4 __attribute__((ext_vector_type(4)));

// scale = HD^-0.5 folded with log2(e): softmax runs in exp2 domain
#define QSCALE (0.17677669529663687f * 1.4426950408889634f)

__device__ __forceinline__ unsigned pk_bf16(float a, float b) {
  __hip_bfloat162 h = __float22bfloat162_rn(make_float2(a, b));
  unsigned u; __builtin_memcpy(&u, &h, 4); return u;
}

__device__ __forceinline__ short8 cvt8(float4 a, float4 b) {
  union { short8 s; unsigned u[4]; } r;
  r.u[0] = pk_bf16(a.x, a.y); r.u[1] = pk_bf16(a.z, a.w);
  r.u[2] = pk_bf16(b.x, b.y); r.u[3] = pk_bf16(b.z, b.w);
  return r.s;
}

// ---------------------------------------------------------------------------
// Cast weights fp32 -> bf16, FRAGMENT-MAJOR swizzle:
// unit(row,col) = ((row>>4)*(Kd/32) + (col>>5))*64 + ((col>>3)&3)*16 + (row&15)
// -> a wave's wf load is one contiguous 1KB segment. QSCALE folded into q_w.
// sr_w additionally gets K permuted to QUADRANT-MAJOR: col' = q*256 + c.
// ---------------------------------------------------------------------------
__global__ __launch_bounds__(256) void cast_weights(
    const float* __restrict__ q_w, const float* __restrict__ kv_w,
    const float* __restrict__ sr_w, const float* __restrict__ proj_w,
    unsigned short* __restrict__ q_wbf, unsigned short* __restrict__ kv_wbf,
    unsigned short* __restrict__ sr_wbf, unsigned short* __restrict__ proj_wbf) {
  const int e = (blockIdx.x * 256 + threadIdx.x) * 8;
  if (e >= 196608 && e < 458752) {
    // sr_w: 8 consecutive src elems = (row, c0..c0+1, q0..3), c0 even
    const int off = e - 196608;
    const int row = off >> 10;
    const int wr = off & 1023;
    const int c0 = (wr >> 3) * 2;
    float4 a = *(const float4*)&sr_w[off];
    float4 b = *(const float4*)&sr_w[off + 4];
    const float v[8] = {a.x, a.y, a.z, a.w, b.x, b.y, b.z, b.w};
    const int base = (row >> 4) * 32;   // Kd/32 = 32
#pragma unroll
    for (int q = 0; q < 4; ++q) {
      const int unit = (base + q * 8 + (c0 >> 5)) * 64 + ((c0 >> 3) & 3) * 16 + (row & 15);
      *(unsigned*)&sr_wbf[unit * 8 + (c0 & 7)] = pk_bf16(v[q], v[4 + q]);
    }
    return;
  }
  const float* src; unsigned short* dst; int off; float sc = 1.f;
  if (e < 65536)       { src = q_w;    dst = q_wbf;    off = e;          sc = QSCALE; }
  else if (e < 196608) { src = kv_w;   dst = kv_wbf;   off = e - 65536; }
  else                 { src = proj_w; dst = proj_wbf; off = e - 458752; }
  const int row = off >> 8;
  const int col = off & 255;
  const int unit = ((row >> 4) * 8 + (col >> 5)) * 64 + ((col >> 3) & 3) * 16 + (row & 15);
  float4 a = *(const float4*)&src[off];
  float4 b = *(const float4*)&src[off + 4];
  a.x *= sc; a.y *= sc; a.z *= sc; a.w *= sc;
  b.x *= sc; b.y *= sc; b.z *= sc; b.w *= sc;
  *(short8*)&dst[unit * 8] = cvt8(a, b);
}

// X-tile LDS layout (tokens x 32 16B-units, 33-unit skew)
#define XU16(t, u) (((t) * 33 + (u)) * 8)

// ---------------------------------------------------------------------------
// SR-conv + LN + KV projection ONLY (Q moved into attn_proj).
// Grid 256 x 512 thr (8 waves -- R4-proven split): conv 2 ct/wave full-K,
// LN on tid<256, KV waves 0-3 -> K, 4-7 -> V.
// ---------------------------------------------------------------------------
__global__ __launch_bounds__(512) void qconv_gemm(const float* __restrict__ x,
    const unsigned short* __restrict__ sr_wbf, const float* __restrict__ sr_b,
    const float* __restrict__ ln_g, const float* __restrict__ ln_b,
    const unsigned short* __restrict__ kv_wbf, const float* __restrict__ kv_b,
    unsigned short* __restrict__ kbf, unsigned short* __restrict__ vtbf) {
  __shared__ unsigned short sm[20736];
  const int tid = threadIdx.x, w = tid >> 6, ln = tid & 63;
  const int l15 = ln & 15, qd = ln >> 4;
  unsigned short* xs = sm + 16512;
  const int gt0 = blockIdx.x * 16;
  const int b = gt0 >> 10, tl = gt0 & 1023;
  const int ti = (tl & 1023) >> 5;
  const int cbase = 2 * (tl & 31);
  // coalesced patch staging: 64 x-tokens (2 rows x 32 cols) x 256 ch fp32.
#pragma unroll
  for (int it = 0; it < 4; ++it) {
    const int g = it * 512 + tid;     // 0..2047 16B-units
    const int xt = g >> 5, u = g & 31;
    const int di = xt >> 5, cj = xt & 31;
    const int row = (2 * ti + di) * 64 + cbase + cj;
    const float* s = &x[((size_t)b * NN + row) * CCH + u * 8];
    float4 a = *(const float4*)s;
    float4 b2 = *(const float4*)(s + 4);
    const int tk = cj >> 1, q = di * 2 + (cj & 1);
    *(short8*)(sm + (tk * 129 + q * 32 + u) * 8) = cvt8(a, b2);
  }
  __syncthreads();
  floatx4 cacc[2];
#pragma unroll
  for (int ct = 0; ct < 2; ++ct) for (int r = 0; r < 4; ++r) cacc[ct][r] = 0.f;
  const unsigned short* wbc = sr_wbf + ln * 8;
#pragma unroll
  for (int kc = 0; kc < 32; ++kc) {
    short8 xf = *(const short8*)(sm + (l15 * 129 + kc * 4 + qd) * 8);
#pragma unroll
    for (int ct = 0; ct < 2; ++ct) {
      short8 wf = *(const short8*)(wbc + ((size_t)((w * 2 + ct) * 32 + kc)) * 512);
      cacc[ct] = __builtin_amdgcn_mfma_f32_16x16x32_bf16(wf, xf, cacc[ct], 0, 0, 0);
    }
  }
  __syncthreads();
  float* ft = (float*)sm;
#pragma unroll
  for (int ct = 0; ct < 2; ++ct) {
    float4 o;
    o.x = cacc[ct][0]; o.y = cacc[ct][1]; o.z = cacc[ct][2]; o.w = cacc[ct][3];
    *(float4*)&ft[l15 * 260 + (w * 2 + ct) * 16 + qd * 4] = o;
  }
  __syncthreads();
  if (tid < 256) {
    const int tk = tid >> 4, l16 = tid & 15;
    float v[16];
    float4* vv = (float4*)v;
#pragma unroll
    for (int m = 0; m < 4; ++m) {
      float4 t = *(float4*)&ft[tk * 260 + l16 * 16 + m * 4];
      float4 sb = *(const float4*)&sr_b[l16 * 16 + m * 4];
      t.x += sb.x; t.y += sb.y; t.z += sb.z; t.w += sb.w;
      vv[m] = t;
    }
    float s1 = 0.f, s2 = 0.f;
#pragma unroll
    for (int i = 0; i < 16; ++i) { s1 += v[i]; s2 += v[i] * v[i]; }
#pragma unroll
    for (int off = 1; off < 16; off <<= 1) {
      s1 += __shfl_xor(s1, off);
      s2 += __shfl_xor(s2, off);
    }
    const float mu = s1 * (1.f / 256.f);
    const float rstd = rsqrtf(s2 * (1.f / 256.f) - mu * mu + EPS_LN);
#pragma unroll
    for (int m = 0; m < 2; ++m) {
      float4 ga = *(const float4*)&ln_g[l16 * 16 + m * 8];
      float4 gb = *(const float4*)&ln_g[l16 * 16 + m * 8 + 4];
      float4 ba = *(const float4*)&ln_b[l16 * 16 + m * 8];
      float4 bb = *(const float4*)&ln_b[l16 * 16 + m * 8 + 4];
      float4 oa, ob;
      oa.x = (vv[m * 2].x - mu) * rstd * ga.x + ba.x;
      oa.y = (vv[m * 2].y - mu) * rstd * ga.y + ba.y;
      oa.z = (vv[m * 2].z - mu) * rstd * ga.z + ba.z;
      oa.w = (vv[m * 2].w - mu) * rstd * ga.w + ba.w;
      ob.x = (vv[m * 2 + 1].x - mu) * rstd * gb.x + bb.x;
      ob.y = (vv[m * 2 + 1].y - mu) * rstd * gb.y + bb.y;
      ob.z = (vv[m * 2 + 1].z - mu) * rstd * gb.z + bb.z;
      ob.w = (vv[m * 2 + 1].w - mu) * rstd * gb.w + bb.w;
      *(short8*)(xs + XU16(tk, l16 * 2 + m)) = cvt8(oa, ob);
    }
  }
  __syncthreads();
  // KV GEMM: waves 0-3 -> K, waves 4-7 -> V, 4 ct (64 ch) each
  const bool isV = (w >= 4);
  const int c16b = (w & 3) * 4;
  floatx4 kacc[4];
#pragma unroll
  for (int ct = 0; ct < 4; ++ct) for (int r = 0; r < 4; ++r) kacc[ct][r] = 0.f;
  const unsigned short* wb = kv_wbf + (size_t)(isV ? 16 + c16b : c16b) * 4096 + ln * 8;
  if (!isV) {
#pragma unroll
    for (int kc = 0; kc < 8; ++kc) {
      short8 xf = *(const short8*)(xs + XU16(l15, kc * 4 + qd));
#pragma unroll
      for (int ct = 0; ct < 4; ++ct) {
        short8 wf = *(const short8*)(wb + ((size_t)ct * 4096 + kc * 512));
        kacc[ct] = __builtin_amdgcn_mfma_f32_16x16x32_bf16(wf, xf, kacc[ct], 0, 0, 0);
      }
    }
    const int tok = tl + l15;
#pragma unroll
    for (int ct = 0; ct < 4; ++ct) {
      const int ch = (c16b + ct) * 16 + qd * 4;
      float4 bb = *(const float4*)&kv_b[ch];
      uint2 u;
      u.x = pk_bf16(kacc[ct][0] + bb.x, kacc[ct][1] + bb.y);
      u.y = pk_bf16(kacc[ct][2] + bb.z, kacc[ct][3] + bb.w);
      const int h = ch >> 5, d0 = ch & 31;
      *(uint2*)&kbf[((size_t)(b * HEADS + h) * NKV + tok) * HD + d0] = u;
    }
  } else {
#pragma unroll
    for (int kc = 0; kc < 8; ++kc) {
      short8 xf = *(const short8*)(xs + XU16(l15, kc * 4 + qd));
#pragma unroll
      for (int ct = 0; ct < 4; ++ct) {
        short8 wf = *(const short8*)(wb + ((size_t)ct * 4096 + kc * 512));
        kacc[ct] = __builtin_amdgcn_mfma_f32_16x16x32_bf16(xf, wf, kacc[ct], 0, 0, 0);
      }
    }
    // frag-major V store
    const int ccv = tl >> 6;
    const int base6 = (tl & 63) + qd * 4;
    const int kg = (base6 >> 5) & 1, kq = (base6 >> 3) & 3, j0 = base6 & 7;
#pragma unroll
    for (int ct = 0; ct < 4; ++ct) {
      const int vc = (w - 4) * 64 + ct * 16 + l15;
      const float bb = kv_b[vc + 256];
      uint2 u;
      u.x = pk_bf16(kacc[ct][0] + bb, kacc[ct][1] + bb);
      u.y = pk_bf16(kacc[ct][2] + bb, kacc[ct][3] + bb);
      const int hh = vc >> 5, d = vc & 31;
      const int half = d >> 4, dl = d & 15;
      const int unit = ((ccv * 2 + kg) * 2 + half) * 64 + kq * 16 + dl;
      *(uint2*)&vtbf[(size_t)(b * HEADS + hh) * 32768 + unit * 8 + j0] = u;
    }
  }
}

// ---------------------------------------------------------------------------
// FUSED Q-projection + flash attention + output projection (v11).
// Block = 512 thr (8 waves), 64 tokens x all 8 heads; wave = head.
// NEW: Q computed IN-BLOCK (wave w projects head w's 32 ch from a shared
// X tile: 64 MFMAs/wave, wave-private LDS round trip, no barrier) --
// removes the 16 MB qbf HBM round-trip and qconv's entire Q dispatch round.
// LDS 144 KB, disjoint: [X 33KB | P 68KB | Q 20KB]; X reused for proj
// staging after the chunk-loop barrier. 1 block/CU (unchanged, VGPR-bound).
// ---------------------------------------------------------------------------
__global__ __launch_bounds__(512) void attn_proj(
    const float* __restrict__ x,
    const unsigned short* __restrict__ q_wbf, const float* __restrict__ q_b,
    const unsigned short* __restrict__ kbf,
    const unsigned short* __restrict__ vtbf,
    const unsigned short* __restrict__ p_wbf, const float* __restrict__ p_b,
    float* __restrict__ out) {
  __shared__ unsigned short sm[72192];   // 144384 B: X[0,16896) P[16896,51712) Q[51712,72192) shorts
  const int tid = threadIdx.x, w = tid >> 6, ln = tid & 63;
  const int l15 = ln & 15, qd = ln >> 4;
  const int g0 = blockIdx.x * 64;
  const int b = g0 >> 12, trow0 = g0 & 4095;
  const int bh = b * HEADS + w;
  const unsigned short* kbase = kbf + (size_t)bh * NKV * HD;
  const unsigned short* vfb = vtbf + (size_t)bh * 32768;

  // ---- stage X (64 tokens, fp32 -> bf16, shared by all 8 heads) ----
  const float* Xg = x + (size_t)g0 * 256;
#pragma unroll
  for (int j = 0; j < 4; ++j) {
    const int idx = j * 512 + tid;
    const int tok = idx >> 5, u = idx & 31;
    float4 a = *(const float4*)(Xg + (size_t)tok * 256 + u * 8);
    float4 b2 = *(const float4*)(Xg + (size_t)tok * 256 + u * 8 + 4);
    *(short8*)(sm + XU16(tok, u)) = cvt8(a, b2);
  }
  __syncthreads();

  // ---- Q projection for own head: 64 tok x 32 ch, wave-private ----
  unsigned short* qls = sm + 51712 + w * 2560;   // 64 tok x 5-unit stride
  {
    floatx4 qacc[4][2];
#pragma unroll
    for (int tt = 0; tt < 4; ++tt)
#pragma unroll
      for (int ct = 0; ct < 2; ++ct)
        for (int r = 0; r < 4; ++r) qacc[tt][ct][r] = 0.f;
    const unsigned short* wb = q_wbf + (size_t)(2 * w) * 4096 + ln * 8;
#pragma unroll
    for (int kc = 0; kc < 8; ++kc) {
      short8 wf0 = *(const short8*)(wb + kc * 512);
      short8 wf1 = *(const short8*)(wb + (8 + kc) * 512);
#pragma unroll
      for (int tt = 0; tt < 4; ++tt) {
        short8 xf = *(const short8*)(sm + XU16(tt * 16 + l15, kc * 4 + qd));
        qacc[tt][0] = __builtin_amdgcn_mfma_f32_16x16x32_bf16(wf0, xf, qacc[tt][0], 0, 0, 0);
        qacc[tt][1] = __builtin_amdgcn_mfma_f32_16x16x32_bf16(wf1, xf, qacc[tt][1], 0, 0, 0);
      }
    }
#pragma unroll
    for (int tt = 0; tt < 4; ++tt)
#pragma unroll
      for (int ct = 0; ct < 2; ++ct) {
        const int ch = w * 32 + ct * 16 + qd * 4;
        float4 bb = *(const float4*)&q_b[ch];
        uint2 u;
        u.x = pk_bf16(qacc[tt][ct][0] + bb.x * QSCALE, qacc[tt][ct][1] + bb.y * QSCALE);
        u.y = pk_bf16(qacc[tt][ct][2] + bb.z * QSCALE, qacc[tt][ct][3] + bb.w * QSCALE);
        *(uint2*)(qls + ((tt * 16 + l15) * 5 + ct * 2 + (qd >> 1)) * 8 + (qd & 1) * 4) = u;
      }
  }
  // same-wave LDS round trip (lgkmcnt ordering; no barrier needed)
  short8 qf[4];
#pragma unroll
  for (int qt = 0; qt < 4; ++qt)
    qf[qt] = *(const short8*)(qls + ((qt * 16 + l15) * 5 + qd) * 8);

  const short8 ones = {16256, 16256, 16256, 16256, 16256, 16256, 16256, 16256};
  floatx4 a0[4], a1[4], al[4];
#pragma unroll
  for (int qt = 0; qt < 4; ++qt)
#pragma unroll
    for (int r = 0; r < 4; ++r) { a0[qt][r] = 0.f; a1[qt][r] = 0.f; al[qt][r] = 0.f; }
  const int pu = 2112 + w * 544;   // P base in 16B units (after X region)

  short8 kfA[4], vA[4], kfB[4], vB[4];
#define LOADKV(KF, VV, CC) do {                                               \
    const unsigned short* kp = kbase + ((size_t)(CC) * 64 + l15) * HD + qd * 8; \
    _Pragma("unroll")                                                          \
    for (int t = 0; t < 4; ++t) (KF)[t] = *(const short8*)(kp + t * 16 * HD);  \
    const unsigned short* vp = vfb + ((size_t)(CC) * 256 + ln) * 8;            \
    _Pragma("unroll")                                                          \
    for (int u = 0; u < 4; ++u) (VV)[u] = *(const short8*)(vp + u * 512);      \
  } while (0)

#define CHUNK(KF, VV) do {                                                     \
    _Pragma("unroll")                                                          \
    for (int qt = 0; qt < 4; ++qt) {                                           \
      const int pq = pu + qt * 136;                                            \
      floatx4 s[4];                                                            \
      _Pragma("unroll")                                                        \
      for (int t = 0; t < 4; ++t) {                                            \
        floatx4 z; for (int r = 0; r < 4; ++r) z[r] = 0.f;                     \
        s[t] = __builtin_amdgcn_mfma_f32_16x16x32_bf16((KF)[t], qf[qt], z, 0, 0, 0); \
      }                                                                        \
      _Pragma("unroll")                                                        \
      for (int t = 0; t < 4; ++t) {                                            \
        uint2 pk;                                                              \
        pk.x = pk_bf16(__builtin_amdgcn_exp2f(s[t][0]), __builtin_amdgcn_exp2f(s[t][1])); \
        pk.y = pk_bf16(__builtin_amdgcn_exp2f(s[t][2]), __builtin_amdgcn_exp2f(s[t][3])); \
        const int unit = pq + (t >> 1) * 68 + ((t & 1) * 2 + (qd >> 1)) * 16 + l15; \
        *(uint2*)(sm + unit * 8 + (qd & 1) * 4) = pk;                          \
      }                                                                        \
      _Pragma("unroll")                                                        \
      for (int kg = 0; kg < 2; ++kg) {                                         \
        short8 pf = *(const short8*)(sm + (pq + kg * 68 + ln) * 8);            \
        a0[qt] = __builtin_amdgcn_mfma_f32_16x16x32_bf16((VV)[kg * 2], pf, a0[qt], 0, 0, 0);     \
        a1[qt] = __builtin_amdgcn_mfma_f32_16x16x32_bf16((VV)[kg * 2 + 1], pf, a1[qt], 0, 0, 0); \
        al[qt] = __builtin_amdgcn_mfma_f32_16x16x32_bf16(ones, pf, al[qt], 0, 0, 0);             \
      }                                                                        \
    }                                                                          \
  } while (0)

  LOADKV(kfA, vA, 0);
  for (int cc = 0; cc < 16; cc += 2) {
    LOADKV(kfB, vB, cc + 1);
    CHUNK(kfA, vA);
    if (cc + 2 < 16) LOADKV(kfA, vA, cc + 2);
    CHUNK(kfB, vB);
  }
#undef LOADKV
#undef CHUNK

  // ---- all waves done with P and X -> stage normalized attn-out into X region
  __syncthreads();
#pragma unroll
  for (int qt = 0; qt < 4; ++qt) {
    const float inv = 1.f / al[qt][0];
    const int t = qt * 16 + l15;
    const int u0 = w * 4 + (qd >> 1);
    uint2 v0, v1;
    v0.x = pk_bf16(a0[qt][0] * inv, a0[qt][1] * inv);
    v0.y = pk_bf16(a0[qt][2] * inv, a0[qt][3] * inv);
    v1.x = pk_bf16(a1[qt][0] * inv, a1[qt][1] * inv);
    v1.y = pk_bf16(a1[qt][2] * inv, a1[qt][3] * inv);
    *(uint2*)(sm + XU16(t, u0) + (qd & 1) * 4) = v0;
    *(uint2*)(sm + XU16(t, u0 + 2) + (qd & 1) * 4) = v1;
  }
  __syncthreads();

  // ---- output projection in-block ----
  const int cb = w & 3, th = w >> 2;
  floatx4 pacc[2][4];
#pragma unroll
  for (int tt = 0; tt < 2; ++tt)
#pragma unroll
    for (int ct = 0; ct < 4; ++ct) for (int r = 0; r < 4; ++r) pacc[tt][ct][r] = 0.f;
  const unsigned short* wb = p_wbf + (size_t)(cb * 4) * 4096 + ln * 8;
#pragma unroll
  for (int kc = 0; kc < 8; ++kc) {
    short8 wf[4];
#pragma unroll
    for (int ct = 0; ct < 4; ++ct) wf[ct] = *(const short8*)(wb + (ct * 8 + kc) * 512);
#pragma unroll
    for (int tt = 0; tt < 2; ++tt) {
      short8 xf = *(const short8*)(sm + XU16(th * 32 + tt * 16 + l15, kc * 4 + qd));
#pragma unroll
      for (int ct = 0; ct < 4; ++ct)
        pacc[tt][ct] = __builtin_amdgcn_mfma_f32_16x16x32_bf16(wf[ct], xf, pacc[tt][ct], 0, 0, 0);
    }
  }
  const int chb = cb * 64;
#pragma unroll
  for (int tt = 0; tt < 2; ++tt) {
    const long tok = (long)g0 + th * 32 + tt * 16 + l15;
#pragma unroll
    for (int ct = 0; ct < 4; ++ct) {
      const int ch = chb + ct * 16 + qd * 4;
      float4 bb = *(const float4*)&p_b[ch];
      float4 o;
      o.x = pacc[tt][ct][0] + bb.x; o.y = pacc[tt][ct][1] + bb.y;
      o.z = pacc[tt][ct][2] + bb.z; o.w = pacc[tt][ct][3] + bb.w;
      *(float4*)&out[(size_t)tok * 256 + ch] = o;
    }
  }
}

// ---------------------------------------------------------------------------
extern "C" void kernel_launch(void* const* d_in, const int* in_sizes, int n_in,
                              void* d_out, int out_size, void* d_ws, size_t ws_size,
                              hipStream_t stream) {
  const float* x      = (const float*)d_in[0];
  const float* q_w    = (const float*)d_in[1];
  const float* q_b    = (const float*)d_in[2];
  const float* kv_w   = (const float*)d_in[3];
  const float* kv_b   = (const float*)d_in[4];
  const float* sr_w   = (const float*)d_in[5];
  const float* sr_b   = (const float*)d_in[6];
  const float* ln_g   = (const float*)d_in[7];
  const float* ln_b   = (const float*)d_in[8];
  const float* proj_w = (const float*)d_in[9];
  const float* proj_b = (const float*)d_in[10];
  float* out = (float*)d_out;

  char* base = (char*)d_ws;
  const size_t MB = 1048576;
  unsigned short* q_wbf    = (unsigned short*)(base);                 // 128 KB
  unsigned short* kv_wbf   = (unsigned short*)(base + 131072);        // 256 KB
  unsigned short* sr_wbf   = (unsigned short*)(base + 393216);        // 512 KB
  unsigned short* proj_wbf = (unsigned short*)(base + 917504);        // 128 KB
  unsigned short* k_bf     = (unsigned short*)(base + 9 * MB);        // 2 MB
  unsigned short* vt_bf    = (unsigned short*)(base + 11 * MB);       // 2 MB

  cast_weights<<<256, 256, 0, stream>>>(q_w, kv_w, sr_w, proj_w,
                                        q_wbf, kv_wbf, sr_wbf, proj_wbf);
  qconv_gemm<<<256, 512, 0, stream>>>(x, sr_wbf, sr_b, ln_g, ln_b,
                                      kv_wbf, kv_b, k_bf, vt_bf);
  attn_proj<<<256, 512, 0, stream>>>(x, q_wbf, q_b, k_bf, vt_bf,
                                     proj_wbf, proj_b, out);
}